// Round 15
// baseline (253.971 us; speedup 1.0000x reference)
//
#include <hip/hip_runtime.h>
#include <cstdint>
#include <cstddef>

// ---------------- types ----------------
typedef __bf16 bf16x8 __attribute__((ext_vector_type(8)));
typedef __bf16 bf16x4 __attribute__((ext_vector_type(4)));
typedef float  f32x4  __attribute__((ext_vector_type(4)));
typedef short  s16x4  __attribute__((ext_vector_type(4)));

#define DIMD 1024
#define SEQ  2048
#define NB   2
#define NH   16
#define HD   64
#define QKVN 1536   // 1024 + 2*256
#define VOFF 1280   // DIMD + 256
#define VSTR 2080   // padded V^T row stride (4160B: breaks L2 channel aliasing)
#define CSC  0.18033688011112042f   // 0.125 * log2(e), folded into q in GEMM1

// async global->LDS (16B per lane, wave-uniform LDS base)
typedef __attribute__((address_space(1))) const void* as1_cvp;
typedef __attribute__((address_space(3))) void* as3_vp;
#define GLL16(g, l) __builtin_amdgcn_global_load_lds((as1_cvp)(const void*)(g), (as3_vp)(void*)(l), 16, 0, 0)

// ---------------- fused prep: x->bf16 cvt + Wqkv^T + Wout^T (one launch) ----------------
__global__ __launch_bounds__(256) void prep(
    const float* __restrict__ x, __bf16* __restrict__ xb,
    const float* __restrict__ Wqkv, __bf16* __restrict__ wqkvT,
    const float* __restrict__ Wout, __bf16* __restrict__ woutT)
{
    __shared__ float t[32][33];
    const int bidx = blockIdx.x;
    const int tid  = threadIdx.x;

    if (bidx < 4096) {                       // cvt: 4096*256 = 1M float4 = 4M elems
        int i = bidx * 256 + tid;
        float4 v = reinterpret_cast<const float4*>(x)[i];
        bf16x4 o;
        o[0] = (__bf16)v.x; o[1] = (__bf16)v.y; o[2] = (__bf16)v.z; o[3] = (__bf16)v.w;
        reinterpret_cast<bf16x4*>(xb)[i] = o;
        return;
    }

    const float* in; __bf16* out; int C, bx, by;
    if (bidx < 5632) {
        int idx = bidx - 4096;
        in = Wqkv; out = wqkvT; C = QKVN;
        bx = idx % 48; by = idx / 48;        // 48 x 32 tiles
    } else {
        int idx = bidx - 5632;
        in = Wout; out = woutT; C = DIMD;
        bx = idx & 31; by = idx >> 5;        // 32 x 32 tiles
    }
    const int tx = tid & 31, ty = tid >> 5;  // (32, 8)
#pragma unroll
    for (int i = 0; i < 32; i += 8)
        t[ty + i][tx] = in[(size_t)(by * 32 + ty + i) * C + bx * 32 + tx];
    __syncthreads();
#pragma unroll
    for (int i = 0; i < 32; i += 8)
        out[(size_t)(bx * 32 + ty + i) * DIMD + by * 32 + tx] = (__bf16)t[tx][ty + i];
}

// ---------------- bf16 [S][64] V-slice of qkv -> bf16 Vt[z][64][VSTR] ----------------
__global__ void transpose_v(const __bf16* __restrict__ qkv, __bf16* __restrict__ vtg) {
    __shared__ __bf16 t[32][34];
    const int z = blockIdx.z;           // b*4 + kh
    const int b = z >> 2, kh = z & 3;
    const int s0 = blockIdx.x * 32, d0 = blockIdx.y * 32;
    const int tx = threadIdx.x, ty = threadIdx.y;   // (32, 8)
    const __bf16* src = qkv + (size_t)b * SEQ * QKVN + VOFF + kh * HD;
#pragma unroll
    for (int i = 0; i < 32; i += 8)
        t[ty + i][tx] = src[(size_t)(s0 + ty + i) * QKVN + d0 + tx];
    __syncthreads();
    __bf16* dst = vtg + ((size_t)z * HD + d0) * VSTR + s0;
#pragma unroll
    for (int i = 0; i < 32; i += 8)
        dst[(size_t)(ty + i) * VSTR + tx] = t[tx][ty + i];
}

// ---------------- bf16 GEMM, 128x64 tile (occupancy-tuned m97 staging) ----------------
// 1D grid, bijective XCD swizzle; 4 waves (2Mx2N), wave = 64x32 (4x2 frags).
template<int OUT_BF16, int QSCALE>
__global__ __launch_bounds__(256) void gemm_bf16(
    const __bf16* __restrict__ A, const __bf16* __restrict__ Bt,
    const float* __restrict__ bias, void* __restrict__ Cout,
    int M, int N, int K, int nx)
{
    __shared__ __bf16 Als[128 * 32];   // row*32 + k (64B rows)
    __shared__ __bf16 Bls[64 * 32];
    const int tid  = threadIdx.x;
    const int lane = tid & 63;
    const int wave = tid >> 6;
    const int lo = lane & 15, hi = lane >> 4;

    const int lin = blockIdx.x;
    const int cpx = gridDim.x >> 3;                    // grid % 8 == 0
    const int swz = (lin & 7) * cpx + (lin >> 3);      // XCD-contiguous
    const int bm = (swz / nx) * 128, bn = (swz % nx) * 64;
    const int wr = (wave >> 1) * 64, wc = (wave & 1) * 32;

    const __bf16* gA = A  + (size_t)(bm + wave * 16 + (lane >> 2)) * K + (lane & 3) * 8;
    const __bf16* gB = Bt + (size_t)(bn + wave * 16 + (lane >> 2)) * K + (lane & 3) * 8;
    __bf16* lA = &Als[wave * 16 * 32];
    __bf16* lB = &Bls[wave * 16 * 32];

    f32x4 acc[4][2] = {};

    for (int k0 = 0; k0 < K; k0 += 32) {
        __syncthreads();
        GLL16(gA + k0,                  lA);
        GLL16(gA + k0 + (size_t)64 * K, lA + 2048);
        GLL16(gB + k0,                  lB);
        __syncthreads();

        bf16x8 af[4], bfr[2];
#pragma unroll
        for (int i = 0; i < 4; i++)
            af[i] = *reinterpret_cast<const bf16x8*>(&Als[(wr + i * 16 + lo) * 32 + hi * 8]);
#pragma unroll
        for (int j = 0; j < 2; j++)
            bfr[j] = *reinterpret_cast<const bf16x8*>(&Bls[(wc + j * 16 + lo) * 32 + hi * 8]);
#pragma unroll
        for (int i = 0; i < 4; i++)
#pragma unroll
            for (int j = 0; j < 2; j++)
                acc[i][j] = __builtin_amdgcn_mfma_f32_16x16x32_bf16(af[i], bfr[j], acc[i][j], 0, 0, 0);
    }

#pragma unroll
    for (int j = 0; j < 2; j++) {
        int col = bn + wc + j * 16 + lo;
        float bv = bias[col];
#pragma unroll
        for (int i = 0; i < 4; i++) {
            int row0 = bm + wr + i * 16 + hi * 4;
#pragma unroll
            for (int rr = 0; rr < 4; rr++) {
                float v = acc[i][j][rr] + bv;
                if (QSCALE && col < DIMD) v *= CSC;
                if (OUT_BF16) ((__bf16*)Cout)[(size_t)(row0 + rr) * N + col] = (__bf16)v;
                else          ((float* )Cout)[(size_t)(row0 + rr) * N + col] = v;
            }
        }
    }
}

// ---------------- causal GQA flash attention ----------------
// r10 skeleton + P-in-register PV + double-buffered K/V staging.
// 512 blocks x 512 threads = 8 waves = 4 heads x 2 key-parities. bid&7 = b*4+kh
// (XCD pin). Each wave handles tiles A=p, B=127-p (16 q-rows each) over its
// parity's 64-key chunks. 128-key super-chunks DOUBLE-buffered in LDS
// (K[128][64], Vt[64][128], XOR-pre-swizzled source): STAGE(s+1) issues before
// compute(s), so the barrier's vmcnt drain is covered by compute. One barrier/sc.
// Swapped QK^T gives lane P[q=lo][k=hi*4+r] == the 16x16x16 mfma B-fragment ->
// PV runs with P in-register (no P LDS round-trip); V is the A-operand (b64
// reads, shared by both tiles). Fixed-max exp2 softmax -> split-K = pure sum;
// parity partials combined through dead K/V LDS (1 barrier).
__global__ __launch_bounds__(512, 4) void attn_fwd(
    const __bf16* __restrict__ qkv, const __bf16* __restrict__ vt, __bf16* __restrict__ y)
{
    __shared__ __bf16 Ka[2][8192];        // [buf][key 128][d 64], swizzled 16B units
    __shared__ __bf16 Va[2][8192];        // [buf][d 64][key 128], swizzled 16B units
    const int tid  = threadIdx.x;
    const int wave = tid >> 6, lane = tid & 63;
    const int lo = lane & 15, hi = lane >> 4;
    const int head = wave & 3, par = wave >> 2;

    const int bid = blockIdx.x;
    const int z  = bid & 7;              // b*4 + kh  -> XCD-pinned
    const int b  = z >> 2, kh = z & 3;
    const int p  = bid >> 3;             // 0..63
    const int h  = kh * 4 + head;

    const int TA = p, TB = 127 - p;
    const int qwA = TA * 16, qwB = TB * 16;
    const int cA = (TA >> 2) + 1, cB = (TB >> 2) + 1;   // 64-key chunk counts
    const int nsc = (cB + 1) >> 1;                      // 128-key super-chunks

    const __bf16* base = qkv + (size_t)b * SEQ * QKVN;
    const __bf16* qp = base + h * HD;
    const __bf16* kp = base + DIMD + kh * HD;
    const __bf16* vp = vt + (size_t)z * HD * VSTR;      // [64][VSTR]

    // ---- staging sources (XOR-pre-swizzled; LDS dest linear) ----
    const int srow = lane >> 3;                       // 0..7
    const int sun  = ((lane & 7) ^ srow) * 8;
    const __bf16* kst0 = kp + (size_t)(wave * 16 + srow) * QKVN + sun;
    const __bf16* kst1 = kp + (size_t)(wave * 16 + 8 + srow) * QKVN + sun;
    const int vrow = lane >> 4;                       // 0..3
    const int vun0 = ((lane & 15) ^ vrow) * 8;
    const int vun1 = ((lane & 15) ^ (vrow + 4)) * 8;
    const __bf16* vst0 = vp + (size_t)(wave * 8 + vrow) * VSTR + vun0;
    const __bf16* vst1 = vp + (size_t)(wave * 8 + 4 + vrow) * VSTR + vun1;
    __bf16* kdst = &Ka[0][wave * 1024];
    __bf16* vdst = &Va[0][wave * 1024];

#define STAGE(s, buf)                                              \
    do {                                                           \
        const size_t ko = (size_t)(s) * 128 * QKVN;                \
        const int    vo = (s) * 128;                               \
        GLL16(kst0 + ko, kdst + (buf) * 8192);                     \
        GLL16(kst1 + ko, kdst + (buf) * 8192 + 512);               \
        GLL16(vst0 + vo, vdst + (buf) * 8192);                     \
        GLL16(vst1 + vo, vdst + (buf) * 8192 + 512);               \
    } while (0)

    // ---- swizzled fragment-read offsets ----
    const int xk = lo & 7;
    const int u0 = (hi ^ xk) * 8;          // K d-units hi
    const int u1 = ((hi + 4) ^ xk) * 8;    // K d-units hi+4
    int voff[4];                           // V b64 offsets (verified r11 mapping)
#pragma unroll
    for (int ks = 0; ks < 4; ks++)
        voff[ks] = (((par * 8 + ks * 2 + (hi >> 1)) ^ xk) << 3) + (hi & 1) * 4;

    // Q B-frags (pre-scaled by CSC in GEMM1): lane holds Q[qw+lo][hi*8..+8]
    bf16x8 bQA0 = *reinterpret_cast<const bf16x8*>(qp + (size_t)(qwA + lo) * QKVN + hi * 8);
    bf16x8 bQA1 = *reinterpret_cast<const bf16x8*>(qp + (size_t)(qwA + lo) * QKVN + 32 + hi * 8);
    bf16x8 bQB0 = *reinterpret_cast<const bf16x8*>(qp + (size_t)(qwB + lo) * QKVN + hi * 8);
    bf16x8 bQB1 = *reinterpret_cast<const bf16x8*>(qp + (size_t)(qwB + lo) * QKVN + 32 + hi * 8);

    f32x4 accA[4] = {}, accB[4] = {};
    f32x4 ssvA = {0.f, 0.f, 0.f, 0.f}, ssvB = {0.f, 0.f, 0.f, 0.f};

    STAGE(0, 0);
    __syncthreads();

    int cur = 0;
    for (int s = 0; s < nsc; ++s) {
        if (s + 1 < nsc) STAGE(s + 1, cur ^ 1);   // in flight under compute(s)

        const int ce = 2 * s + par;        // this wave's 64-key chunk index
        const int kt = ce << 6;            // global key base (mask arithmetic)
        const bool aB = (ce < cB), dB = (ce == cB - 1);
        const bool aA = (ce < cA), dA = (ce == cA - 1);

        if (aB) {
            const __bf16* Kb = &Ka[cur][par * 4096];   // this parity's 64 key rows
            const __bf16* Vb = &Va[cur][0];

            // S^T = K Q^T per 16-key subtile; lane gets q=lo, k = kt+16ks+hi*4+r
#pragma unroll
            for (int ks = 0; ks < 4; ks++) {
                const __bf16* Kr = Kb + (ks * 16 + lo) * 64;
                bf16x8 aK0 = *reinterpret_cast<const bf16x8*>(Kr + u0);
                bf16x8 aK1 = *reinterpret_cast<const bf16x8*>(Kr + u1);

                f32x4 svB = {0.f, 0.f, 0.f, 0.f};
                svB = __builtin_amdgcn_mfma_f32_16x16x32_bf16(aK0, bQB0, svB, 0, 0, 0);
                svB = __builtin_amdgcn_mfma_f32_16x16x32_bf16(aK1, bQB1, svB, 0, 0, 0);
                f32x4 svA = {0.f, 0.f, 0.f, 0.f};
                if (aA) {
                    svA = __builtin_amdgcn_mfma_f32_16x16x32_bf16(aK0, bQA0, svA, 0, 0, 0);
                    svA = __builtin_amdgcn_mfma_f32_16x16x32_bf16(aK1, bQA1, svA, 0, 0, 0);
                }

                bf16x4 pkB, pkA;
#pragma unroll
                for (int r = 0; r < 4; r++) {
                    float eB = exp2f(svB[r]);
                    if (dB && (kt + ks * 16 + hi * 4 + r > qwB + lo)) eB = 0.0f;
                    ssvB[r] += eB;
                    pkB[r] = (__bf16)eB;
                }
                if (aA) {
#pragma unroll
                    for (int r = 0; r < 4; r++) {
                        float eA = exp2f(svA[r]);
                        if (dA && (kt + ks * 16 + hi * 4 + r > qwA + lo)) eA = 0.0f;
                        ssvA[r] += eA;
                        pkA[r] = (__bf16)eA;
                    }
                }

                // PV: A = V frag (b64, shared by both tiles), B = pk in-register.
                // D[d][q]: col=lo=q, row=hi*4+r; accX[f] covers d = f*16..+16.
#pragma unroll
                for (int f = 0; f < 4; f++) {
                    bf16x4 vf = *reinterpret_cast<const bf16x4*>(&Vb[(f * 16 + lo) * 128] + voff[ks]);
                    s16x4 vfi = __builtin_bit_cast(s16x4, vf);
                    accB[f] = __builtin_amdgcn_mfma_f32_16x16x16bf16_1k(
                        vfi, __builtin_bit_cast(s16x4, pkB), accB[f], 0, 0, 0);
                    if (aA)
                        accA[f] = __builtin_amdgcn_mfma_f32_16x16x16bf16_1k(
                            vfi, __builtin_bit_cast(s16x4, pkA), accA[f], 0, 0, 0);
                }
            }
        }

        __syncthreads();   // reads of buf(cur) done; STAGE(s+1) drained
        cur ^= 1;
    }
#undef STAGE

    float ssA = (ssvA[0] + ssvA[1]) + (ssvA[2] + ssvA[3]);
    float ssB = (ssvB[0] + ssvB[1]) + (ssvB[2] + ssvB[3]);

    // ---- parity combine (pure sum) through dead K/V LDS, 1 barrier ----
    float* cls = (float*)&Ka[0][0];              // 4 heads x 64 lanes x 144B = 36.9KB
    const int cbase = (head * 64 + lane) * 36;
    if (par == 1) {
#pragma unroll
        for (int f = 0; f < 4; f++) {
            *reinterpret_cast<f32x4*>(&cls[cbase + f * 4])      = accA[f];
            *reinterpret_cast<f32x4*>(&cls[cbase + 16 + f * 4]) = accB[f];
        }
        cls[cbase + 32] = ssA;
        cls[cbase + 33] = ssB;
    }
    __syncthreads();
    if (par == 0) {
#pragma unroll
        for (int f = 0; f < 4; f++) {
            accA[f] += *reinterpret_cast<const f32x4*>(&cls[cbase + f * 4]);
            accB[f] += *reinterpret_cast<const f32x4*>(&cls[cbase + 16 + f * 4]);
        }
        ssA += cls[cbase + 32];
        ssB += cls[cbase + 33];

        // acc: q = lo (lane-local), d = f*16 + hi*4 + r  (r11-verified layout)
        ssA += __shfl_xor(ssA, 16);  ssA += __shfl_xor(ssA, 32);
        ssB += __shfl_xor(ssB, 16);  ssB += __shfl_xor(ssB, 32);
        float invA = 1.0f / ssA, invB = 1.0f / ssB;
        const size_t ybA = (size_t)(b * SEQ + qwA + lo) * DIMD + h * HD + hi * 4;
        const size_t ybB = (size_t)(b * SEQ + qwB + lo) * DIMD + h * HD + hi * 4;
#pragma unroll
        for (int f = 0; f < 4; f++) {
            bf16x4 oa, ob;
#pragma unroll
            for (int r = 0; r < 4; r++) {
                oa[r] = (__bf16)(accA[f][r] * invA);
                ob[r] = (__bf16)(accB[f][r] * invB);
            }
            *reinterpret_cast<bf16x4*>(&y[ybA + f * 16]) = oa;
            *reinterpret_cast<bf16x4*>(&y[ybB + f * 16]) = ob;
        }
    }
}

// ---------------- launcher ----------------
extern "C" void kernel_launch(void* const* d_in, const int* in_sizes, int n_in,
                              void* d_out, int out_size, void* d_ws, size_t ws_size,
                              hipStream_t stream) {
    const float* x    = (const float*)d_in[0];
    const float* Wqkv = (const float*)d_in[1];
    const float* bqkv = (const float*)d_in[2];
    const float* Wout = (const float*)d_in[3];
    const float* bout = (const float*)d_in[4];
    float* out = (float*)d_out;

    char* ws = (char*)d_ws;
    __bf16* xb    = (__bf16*)(ws);                          // 8 MB  (x bf16; later reused as y)
    __bf16* wqkvT = (__bf16*)(ws + ((size_t)8  << 20));     // 3 MB  [1536][1024] (dead after GEMM1)
    __bf16* woutT = (__bf16*)(ws + ((size_t)11 << 20));     // 2 MB  [1024][1024]
    __bf16* qkvb  = (__bf16*)(ws + ((size_t)13 << 20));     // 12 MB [4096][1536]
    __bf16* vtg   = wqkvT;                                  // alias: 2.2 MB Vt[8][64][VSTR]
    __bf16* yb    = xb;                                     // alias: xb dead after GEMM1

    const int M = NB * SEQ;   // 4096

    prep<<<6656, 256, 0, stream>>>(x, xb, Wqkv, wqkvT, Wout, woutT);

    // 128x64 tiles: 768 blocks (3/CU), XCD-swizzled
    gemm_bf16<1, 1><<<(M / 128) * (QKVN / 64), 256, 0, stream>>>(
        xb, wqkvT, bqkv, qkvb, M, QKVN, DIMD, QKVN / 64);

    transpose_v<<<dim3(SEQ / 32, HD / 32, NB * 4), dim3(32, 8), 0, stream>>>(qkvb, vtg);

    attn_fwd<<<512, 512, 0, stream>>>(qkvb, vtg, yb);

    // 128x64 tiles: 512 blocks (2/CU), XCD-swizzled
    gemm_bf16<0, 0><<<(M / 128) * (DIMD / 64), 256, 0, stream>>>(
        yb, woutT, bout, out, M, DIMD, DIMD, DIMD / 64);
}

// Round 16
// 94.677 us; speedup vs baseline: 2.6825x; 2.6825x over previous
//
#include <hip/hip_runtime.h>
#include <cstdint>
#include <cstddef>

// ---------------- types ----------------
typedef __bf16 bf16x8 __attribute__((ext_vector_type(8)));
typedef __bf16 bf16x4 __attribute__((ext_vector_type(4)));
typedef float  f32x4  __attribute__((ext_vector_type(4)));

#define DIMD 1024
#define SEQ  2048
#define NB   2
#define NH   16
#define HD   64
#define QKVN 1536   // 1024 + 2*256
#define VOFF 1280   // DIMD + 256
#define VSTR 2080   // padded V^T row stride (4160B: breaks L2 channel aliasing)
#define CSC  0.18033688011112042f   // 0.125 * log2(e), folded into q in GEMM1

// async global->LDS (16B per lane, wave-uniform LDS base)
typedef __attribute__((address_space(1))) const void* as1_cvp;
typedef __attribute__((address_space(3))) void* as3_vp;
#define GLL16(g, l) __builtin_amdgcn_global_load_lds((as1_cvp)(const void*)(g), (as3_vp)(void*)(l), 16, 0, 0)

// ---------------- fused prep: x->bf16 cvt + Wqkv^T + Wout^T (one launch) ----------------
__global__ __launch_bounds__(256) void prep(
    const float* __restrict__ x, __bf16* __restrict__ xb,
    const float* __restrict__ Wqkv, __bf16* __restrict__ wqkvT,
    const float* __restrict__ Wout, __bf16* __restrict__ woutT)
{
    __shared__ float t[32][33];
    const int bidx = blockIdx.x;
    const int tid  = threadIdx.x;

    if (bidx < 4096) {                       // cvt: 4096*256 = 1M float4 = 4M elems
        int i = bidx * 256 + tid;
        float4 v = reinterpret_cast<const float4*>(x)[i];
        bf16x4 o;
        o[0] = (__bf16)v.x; o[1] = (__bf16)v.y; o[2] = (__bf16)v.z; o[3] = (__bf16)v.w;
        reinterpret_cast<bf16x4*>(xb)[i] = o;
        return;
    }

    const float* in; __bf16* out; int C, bx, by;
    if (bidx < 5632) {
        int idx = bidx - 4096;
        in = Wqkv; out = wqkvT; C = QKVN;
        bx = idx % 48; by = idx / 48;        // 48 x 32 tiles
    } else {
        int idx = bidx - 5632;
        in = Wout; out = woutT; C = DIMD;
        bx = idx & 31; by = idx >> 5;        // 32 x 32 tiles
    }
    const int tx = tid & 31, ty = tid >> 5;  // (32, 8)
#pragma unroll
    for (int i = 0; i < 32; i += 8)
        t[ty + i][tx] = in[(size_t)(by * 32 + ty + i) * C + bx * 32 + tx];
    __syncthreads();
#pragma unroll
    for (int i = 0; i < 32; i += 8)
        out[(size_t)(bx * 32 + ty + i) * DIMD + by * 32 + tx] = (__bf16)t[tx][ty + i];
}

// ---------------- bf16 [S][64] V-slice of qkv -> bf16 Vt[z][64][VSTR] ----------------
__global__ void transpose_v(const __bf16* __restrict__ qkv, __bf16* __restrict__ vtg) {
    __shared__ __bf16 t[32][34];
    const int z = blockIdx.z;           // b*4 + kh
    const int b = z >> 2, kh = z & 3;
    const int s0 = blockIdx.x * 32, d0 = blockIdx.y * 32;
    const int tx = threadIdx.x, ty = threadIdx.y;   // (32, 8)
    const __bf16* src = qkv + (size_t)b * SEQ * QKVN + VOFF + kh * HD;
#pragma unroll
    for (int i = 0; i < 32; i += 8)
        t[ty + i][tx] = src[(size_t)(s0 + ty + i) * QKVN + d0 + tx];
    __syncthreads();
    __bf16* dst = vtg + ((size_t)z * HD + d0) * VSTR + s0;
#pragma unroll
    for (int i = 0; i < 32; i += 8)
        dst[(size_t)(ty + i) * VSTR + tx] = t[tx][ty + i];
}

// ---------------- bf16 GEMM, 128x64 tile, BK=64 (XOR-swizzled staging) ----------------
// C[M,N] = A[M,K]*Bt[N,K]^T + bias. 1D grid, bijective XCD swizzle.
// 4 waves (2Mx2N), wave = 64x32 output (4x2 frags). BK=64 halves barrier count
// vs BK=32. 128B LDS rows XOR-swizzled via pre-swizzled GLL source (attn-proven
// pattern): stored unit = orig unit ^ (row&7); frag reads land 2-way (free).
template<int OUT_BF16, int QSCALE>
__global__ __launch_bounds__(256) void gemm_bf16(
    const __bf16* __restrict__ A, const __bf16* __restrict__ Bt,
    const float* __restrict__ bias, void* __restrict__ Cout,
    int M, int N, int K, int nx)
{
    __shared__ __bf16 Als[128 * 64];   // [row][unit^,(8 elems)] swizzled
    __shared__ __bf16 Bls[64 * 64];
    const int tid  = threadIdx.x;
    const int lane = tid & 63;
    const int wave = tid >> 6;
    const int lo = lane & 15, hi = lane >> 4;

    const int lin = blockIdx.x;
    const int cpx = gridDim.x >> 3;                    // grid % 8 == 0
    const int swz = (lin & 7) * cpx + (lin >> 3);      // XCD-contiguous
    const int bm = (swz / nx) * 128, bn = (swz % nx) * 64;
    const int wr = (wave >> 1) * 64, wc = (wave & 1) * 32;

    // staging: instr covers 8 rows (lane>>3), unit lane&7; source unit pre-XORed
    const int srow = lane >> 3;                        // 0..7
    const int sun  = ((lane & 7) ^ srow) * 8;          // elems
    // A: wave w stages rows [32w, 32w+32) via 4 instrs; B: rows [16w,16w+16) via 2
    const __bf16* gA = A  + (size_t)(bm + wave * 32 + srow) * K + sun;
    const __bf16* gB = Bt + (size_t)(bn + wave * 16 + srow) * K + sun;
    __bf16* lA = &Als[wave * 32 * 64];
    __bf16* lB = &Bls[wave * 16 * 64];

    // swizzled fragment-read unit offsets (elems): ksub 0 -> units hi, ksub 1 -> hi+4
    const int xk = lo & 7;
    const int u0 = (hi ^ xk) * 8;
    const int u1 = ((hi + 4) ^ xk) * 8;

    f32x4 acc[4][2] = {};

    for (int k0 = 0; k0 < K; k0 += 64) {
        __syncthreads();
        GLL16(gA + k0,                   lA);
        GLL16(gA + k0 + (size_t)8  * K,  lA + 512);
        GLL16(gA + k0 + (size_t)16 * K,  lA + 1024);
        GLL16(gA + k0 + (size_t)24 * K,  lA + 1536);
        GLL16(gB + k0,                   lB);
        GLL16(gB + k0 + (size_t)8  * K,  lB + 512);
        __syncthreads();

#pragma unroll
        for (int ksub = 0; ksub < 2; ksub++) {
            const int uu = ksub ? u1 : u0;
            bf16x8 af[4], bfr[2];
#pragma unroll
            for (int i = 0; i < 4; i++)
                af[i] = *reinterpret_cast<const bf16x8*>(&Als[(wr + i * 16 + lo) * 64 + uu]);
#pragma unroll
            for (int j = 0; j < 2; j++)
                bfr[j] = *reinterpret_cast<const bf16x8*>(&Bls[(wc + j * 16 + lo) * 64 + uu]);
#pragma unroll
            for (int i = 0; i < 4; i++)
#pragma unroll
                for (int j = 0; j < 2; j++)
                    acc[i][j] = __builtin_amdgcn_mfma_f32_16x16x32_bf16(af[i], bfr[j], acc[i][j], 0, 0, 0);
        }
    }

#pragma unroll
    for (int j = 0; j < 2; j++) {
        int col = bn + wc + j * 16 + lo;
        float bv = bias[col];
#pragma unroll
        for (int i = 0; i < 4; i++) {
            int row0 = bm + wr + i * 16 + hi * 4;
#pragma unroll
            for (int rr = 0; rr < 4; rr++) {
                float v = acc[i][j][rr] + bv;
                if (QSCALE && col < DIMD) v *= CSC;
                if (OUT_BF16) ((__bf16*)Cout)[(size_t)(row0 + rr) * N + col] = (__bf16)v;
                else          ((float* )Cout)[(size_t)(row0 + rr) * N + col] = v;
            }
        }
    }
}

// ---------------- causal GQA flash attention (r14 structure, proven 45.8us) ----------------
// 512 blocks x 512 threads = 8 waves = 4 heads x 2 key-parities. bid&7 = b*4+kh
// (XCD pin). Each wave handles tiles A=p, B=127-p (16 q-rows each) over its
// parity's 64-key chunks. 128-key super-chunks staged once per block
// (K[128][64], Vt[64][128], XOR-swizzled source, single-buffered). Fixed-max
// exp2 softmax -> split-K is a pure sum.
__global__ __launch_bounds__(512, 4) void attn_fwd(
    const __bf16* __restrict__ qkv, const __bf16* __restrict__ vt, __bf16* __restrict__ y)
{
    __shared__ __bf16 Kls[128 * 64];        // [key][d], row-XOR-swizzled 16B units
    __shared__ __bf16 Vls[64 * 128];        // [d][key], row-XOR-swizzled 16B units
    __shared__ __bf16 Pls[8][2][16][72];    // [wave][tile][q][k], 144B rows
    const int tid  = threadIdx.x;
    const int wave = tid >> 6, lane = tid & 63;
    const int lo = lane & 15, hi = lane >> 4;
    const int head = wave & 3, par = wave >> 2;

    const int bid = blockIdx.x;
    const int z  = bid & 7;              // b*4 + kh  -> XCD-pinned
    const int b  = z >> 2, kh = z & 3;
    const int p  = bid >> 3;             // 0..63
    const int h  = kh * 4 + head;

    const int TA = p, TB = 127 - p;
    const int qwA = TA * 16, qwB = TB * 16;
    const int cA = (TA >> 2) + 1, cB = (TB >> 2) + 1;   // 64-key chunk counts
    const int nsc = (cB + 1) >> 1;                      // 128-key super-chunks

    const __bf16* base = qkv + (size_t)b * SEQ * QKVN;
    const __bf16* qp = base + h * HD;
    const __bf16* kp = base + DIMD + kh * HD;
    const __bf16* vp = vt + (size_t)z * HD * VSTR;      // [64][VSTR]

    // ---- staging sources (XOR-pre-swizzled; LDS dest linear) ----
    const int srow = lane >> 3;                       // 0..7
    const int sun  = ((lane & 7) ^ srow) * 8;
    const __bf16* kst0 = kp + (size_t)(wave * 16 + srow) * QKVN + sun;
    const __bf16* kst1 = kp + (size_t)(wave * 16 + 8 + srow) * QKVN + sun;
    const int vrow = lane >> 4;                       // 0..3
    const int vun0 = ((lane & 15) ^ vrow) * 8;
    const int vun1 = ((lane & 15) ^ (vrow + 4)) * 8;
    const __bf16* vst0 = vp + (size_t)(wave * 8 + vrow) * VSTR + vun0;
    const __bf16* vst1 = vp + (size_t)(wave * 8 + 4 + vrow) * VSTR + vun1;
    __bf16* kdst = &Kls[wave * 1024];
    __bf16* vdst = &Vls[wave * 1024];

#define STAGE(s)                                            \
    do {                                                    \
        const size_t ko = (size_t)(s) * 128 * QKVN;         \
        const int    vo = (s) * 128;                        \
        GLL16(kst0 + ko, kdst);                             \
        GLL16(kst1 + ko, kdst + 512);                       \
        GLL16(vst0 + vo, vdst);                             \
        GLL16(vst1 + vo, vdst + 512);                       \
    } while (0)

    // ---- swizzled fragment-read offsets ----
    const int xk = lo & 7;
    const int u0 = (hi ^ xk) * 8;          // K d-units hi
    const int u1 = ((hi + 4) ^ xk) * 8;    // K d-units hi+4
    const int kb = par * 64;               // this parity's key base within tile

    // Q B-frags (pre-scaled by CSC in GEMM1): lane holds Q[qw+lo][hi*8..+8]
    bf16x8 bQA0 = *reinterpret_cast<const bf16x8*>(qp + (size_t)(qwA + lo) * QKVN + hi * 8);
    bf16x8 bQA1 = *reinterpret_cast<const bf16x8*>(qp + (size_t)(qwA + lo) * QKVN + 32 + hi * 8);
    bf16x8 bQB0 = *reinterpret_cast<const bf16x8*>(qp + (size_t)(qwB + lo) * QKVN + hi * 8);
    bf16x8 bQB1 = *reinterpret_cast<const bf16x8*>(qp + (size_t)(qwB + lo) * QKVN + 32 + hi * 8);

    f32x4 accA[4] = {}, accB[4] = {};
    float ssA = 0.0f, ssB = 0.0f;

    STAGE(0);
    __syncthreads();

    for (int s = 0; s < nsc; ++s) {
        const int ce = 2 * s + par;        // this wave's 64-key chunk index
        const int kt = ce << 6;            // global key base (mask arithmetic)
        const bool aB = (ce < cB), dB = (ce == cB - 1);
        const bool aA = (ce < cA), dA = (ce == cA - 1);

        if (aB) {
            // S^T = K Q^T per 16-key subtile; lane gets q=lo, k = kt+16ks+hi*4+r
#pragma unroll
            for (int ks = 0; ks < 4; ks++) {
                const __bf16* Kr = &Kls[(kb + ks * 16 + lo) * 64];
                bf16x8 aK0 = *reinterpret_cast<const bf16x8*>(Kr + u0);
                bf16x8 aK1 = *reinterpret_cast<const bf16x8*>(Kr + u1);

                {   // tile B
                    f32x4 sv = {0.f, 0.f, 0.f, 0.f};
                    sv = __builtin_amdgcn_mfma_f32_16x16x32_bf16(aK0, bQB0, sv, 0, 0, 0);
                    sv = __builtin_amdgcn_mfma_f32_16x16x32_bf16(aK1, bQB1, sv, 0, 0, 0);
                    bf16x4 pk;
#pragma unroll
                    for (int r = 0; r < 4; r++) {
                        float e = exp2f(sv[r]);
                        if (dB && (kt + ks * 16 + hi * 4 + r > qwB + lo)) e = 0.0f;
                        ssB += e;
                        pk[r] = (__bf16)e;
                    }
                    *reinterpret_cast<bf16x4*>(&Pls[wave][1][lo][ks * 16 + hi * 4]) = pk;
                }
                if (aA) {   // tile A — reuses aK0/aK1
                    f32x4 sv = {0.f, 0.f, 0.f, 0.f};
                    sv = __builtin_amdgcn_mfma_f32_16x16x32_bf16(aK0, bQA0, sv, 0, 0, 0);
                    sv = __builtin_amdgcn_mfma_f32_16x16x32_bf16(aK1, bQA1, sv, 0, 0, 0);
                    bf16x4 pk;
#pragma unroll
                    for (int r = 0; r < 4; r++) {
                        float e = exp2f(sv[r]);
                        if (dA && (kt + ks * 16 + hi * 4 + r > qwA + lo)) e = 0.0f;
                        ssA += e;
                        pk[r] = (__bf16)e;
                    }
                    *reinterpret_cast<bf16x4*>(&Pls[wave][0][lo][ks * 16 + hi * 4]) = pk;
                }
            }

            // P x V : V frags shared by both tiles
#pragma unroll
            for (int k2 = 0; k2 < 2; k2++) {
                const int uv = ((8 * par + k2 * 4 + hi) ^ xk) * 8;
                bf16x8 v0 = *reinterpret_cast<const bf16x8*>(&Vls[(0 * 16 + lo) * 128] + uv);
                bf16x8 v1 = *reinterpret_cast<const bf16x8*>(&Vls[(1 * 16 + lo) * 128] + uv);
                bf16x8 v2 = *reinterpret_cast<const bf16x8*>(&Vls[(2 * 16 + lo) * 128] + uv);
                bf16x8 v3 = *reinterpret_cast<const bf16x8*>(&Vls[(3 * 16 + lo) * 128] + uv);
                bf16x8 pB = *reinterpret_cast<const bf16x8*>(&Pls[wave][1][lo][k2 * 32 + hi * 8]);
                accB[0] = __builtin_amdgcn_mfma_f32_16x16x32_bf16(pB, v0, accB[0], 0, 0, 0);
                accB[1] = __builtin_amdgcn_mfma_f32_16x16x32_bf16(pB, v1, accB[1], 0, 0, 0);
                accB[2] = __builtin_amdgcn_mfma_f32_16x16x32_bf16(pB, v2, accB[2], 0, 0, 0);
                accB[3] = __builtin_amdgcn_mfma_f32_16x16x32_bf16(pB, v3, accB[3], 0, 0, 0);
                if (aA) {
                    bf16x8 pA = *reinterpret_cast<const bf16x8*>(&Pls[wave][0][lo][k2 * 32 + hi * 8]);
                    accA[0] = __builtin_amdgcn_mfma_f32_16x16x32_bf16(pA, v0, accA[0], 0, 0, 0);
                    accA[1] = __builtin_amdgcn_mfma_f32_16x16x32_bf16(pA, v1, accA[1], 0, 0, 0);
                    accA[2] = __builtin_amdgcn_mfma_f32_16x16x32_bf16(pA, v2, accA[2], 0, 0, 0);
                    accA[3] = __builtin_amdgcn_mfma_f32_16x16x32_bf16(pA, v3, accA[3], 0, 0, 0);
                }
            }
        }

        __syncthreads();                       // all reads of this super-chunk done
        if (s + 1 < nsc) {
            STAGE(s + 1);
            __syncthreads();                   // staged data visible
        }
    }
#undef STAGE

    // ---- parity combine (pure sum: fixed-max softmax) through LDS (overlays Pls) ----
    float* cls = (float*)&Pls[0][0][0][0];
    const int cbase = (head * 64 + lane) * 36;   // 144B stride, 16B-aligned
    if (par == 1) {
#pragma unroll
        for (int f = 0; f < 4; f++) {
            *reinterpret_cast<f32x4*>(&cls[cbase + f * 4])      = accA[f];
            *reinterpret_cast<f32x4*>(&cls[cbase + 16 + f * 4]) = accB[f];
        }
        cls[cbase + 32] = ssA;
        cls[cbase + 33] = ssB;
    }
    __syncthreads();
    if (par == 0) {
#pragma unroll
        for (int f = 0; f < 4; f++) {
            accA[f] += *reinterpret_cast<f32x4*>(&cls[cbase + f * 4]);
            accB[f] += *reinterpret_cast<f32x4*>(&cls[cbase + 16 + f * 4]);
        }
        ssA += cls[cbase + 32];
        ssB += cls[cbase + 33];

        ssA += __shfl_xor(ssA, 16);  ssA += __shfl_xor(ssA, 32);
        ssB += __shfl_xor(ssB, 16);  ssB += __shfl_xor(ssB, 32);
#pragma unroll
        for (int r = 0; r < 4; r++) {
            float srA = __shfl(ssA, hi * 4 + r);
            float srB = __shfl(ssB, hi * 4 + r);
            float invA = 1.0f / srA, invB = 1.0f / srB;
            int qA = qwA + hi * 4 + r, qB = qwB + hi * 4 + r;
#pragma unroll
            for (int f = 0; f < 4; f++) {
                y[(size_t)(b * SEQ + qA) * DIMD + h * HD + f * 16 + lo] = (__bf16)(accA[f][r] * invA);
                y[(size_t)(b * SEQ + qB) * DIMD + h * HD + f * 16 + lo] = (__bf16)(accB[f][r] * invB);
            }
        }
    }
}

// ---------------- launcher ----------------
extern "C" void kernel_launch(void* const* d_in, const int* in_sizes, int n_in,
                              void* d_out, int out_size, void* d_ws, size_t ws_size,
                              hipStream_t stream) {
    const float* x    = (const float*)d_in[0];
    const float* Wqkv = (const float*)d_in[1];
    const float* bqkv = (const float*)d_in[2];
    const float* Wout = (const float*)d_in[3];
    const float* bout = (const float*)d_in[4];
    float* out = (float*)d_out;

    char* ws = (char*)d_ws;
    __bf16* xb    = (__bf16*)(ws);                          // 8 MB  (x bf16; later reused as y)
    __bf16* wqkvT = (__bf16*)(ws + ((size_t)8  << 20));     // 3 MB  [1536][1024] (dead after GEMM1)
    __bf16* woutT = (__bf16*)(ws + ((size_t)11 << 20));     // 2 MB  [1024][1024]
    __bf16* qkvb  = (__bf16*)(ws + ((size_t)13 << 20));     // 12 MB [4096][1536]
    __bf16* vtg   = wqkvT;                                  // alias: 2.2 MB Vt[8][64][VSTR]
    __bf16* yb    = xb;                                     // alias: xb dead after GEMM1

    const int M = NB * SEQ;   // 4096

    prep<<<6656, 256, 0, stream>>>(x, xb, Wqkv, wqkvT, Wout, woutT);

    // 128x64 tiles, BK=64: 768 blocks (3/CU), XCD-swizzled
    gemm_bf16<1, 1><<<(M / 128) * (QKVN / 64), 256, 0, stream>>>(
        xb, wqkvT, bqkv, qkvb, M, QKVN, DIMD, QKVN / 64);

    transpose_v<<<dim3(SEQ / 32, HD / 32, NB * 4), dim3(32, 8), 0, stream>>>(qkvb, vtg);

    attn_fwd<<<512, 512, 0, stream>>>(qkvb, vtg, yb);

    // 128x64 tiles, BK=64: 512 blocks (2/CU), XCD-swizzled
    gemm_bf16<0, 0><<<(M / 128) * (DIMD / 64), 256, 0, stream>>>(
        yb, woutT, bout, out, M, DIMD, DIMD, DIMD / 64);
}

// Round 17
// 93.530 us; speedup vs baseline: 2.7154x; 1.0123x over previous
//
#include <hip/hip_runtime.h>
#include <cstdint>
#include <cstddef>

// ---------------- types ----------------
typedef __bf16 bf16x8 __attribute__((ext_vector_type(8)));
typedef __bf16 bf16x4 __attribute__((ext_vector_type(4)));
typedef float  f32x4  __attribute__((ext_vector_type(4)));

#define DIMD 1024
#define SEQ  2048
#define NB   2
#define NH   16
#define HD   64
#define QKVN 1536   // 1024 + 2*256
#define VOFF 1280   // DIMD + 256
#define VSTR 2080   // padded V^T row stride (4160B: breaks L2 channel aliasing)
#define CSC  0.18033688011112042f   // 0.125 * log2(e), folded into q in GEMM1

// async global->LDS (16B per lane, wave-uniform LDS base)
typedef __attribute__((address_space(1))) const void* as1_cvp;
typedef __attribute__((address_space(3))) void* as3_vp;
#define GLL16(g, l) __builtin_amdgcn_global_load_lds((as1_cvp)(const void*)(g), (as3_vp)(void*)(l), 16, 0, 0)

// ---------------- fused prep: x->bf16 cvt + Wqkv^T + Wout^T (one launch) ----------------
__global__ __launch_bounds__(256) void prep(
    const float* __restrict__ x, __bf16* __restrict__ xb,
    const float* __restrict__ Wqkv, __bf16* __restrict__ wqkvT,
    const float* __restrict__ Wout, __bf16* __restrict__ woutT)
{
    __shared__ float t[32][33];
    const int bidx = blockIdx.x;
    const int tid  = threadIdx.x;

    if (bidx < 4096) {                       // cvt: 4096*256 = 1M float4 = 4M elems
        int i = bidx * 256 + tid;
        float4 v = reinterpret_cast<const float4*>(x)[i];
        bf16x4 o;
        o[0] = (__bf16)v.x; o[1] = (__bf16)v.y; o[2] = (__bf16)v.z; o[3] = (__bf16)v.w;
        reinterpret_cast<bf16x4*>(xb)[i] = o;
        return;
    }

    const float* in; __bf16* out; int C, bx, by;
    if (bidx < 5632) {
        int idx = bidx - 4096;
        in = Wqkv; out = wqkvT; C = QKVN;
        bx = idx % 48; by = idx / 48;        // 48 x 32 tiles
    } else {
        int idx = bidx - 5632;
        in = Wout; out = woutT; C = DIMD;
        bx = idx & 31; by = idx >> 5;        // 32 x 32 tiles
    }
    const int tx = tid & 31, ty = tid >> 5;  // (32, 8)
#pragma unroll
    for (int i = 0; i < 32; i += 8)
        t[ty + i][tx] = in[(size_t)(by * 32 + ty + i) * C + bx * 32 + tx];
    __syncthreads();
#pragma unroll
    for (int i = 0; i < 32; i += 8)
        out[(size_t)(bx * 32 + ty + i) * DIMD + by * 32 + tx] = (__bf16)t[tx][ty + i];
}

// ---------------- bf16 [S][64] V-slice of qkv -> bf16 Vt[z][64][VSTR] ----------------
__global__ void transpose_v(const __bf16* __restrict__ qkv, __bf16* __restrict__ vtg) {
    __shared__ __bf16 t[32][34];
    const int z = blockIdx.z;           // b*4 + kh
    const int b = z >> 2, kh = z & 3;
    const int s0 = blockIdx.x * 32, d0 = blockIdx.y * 32;
    const int tx = threadIdx.x, ty = threadIdx.y;   // (32, 8)
    const __bf16* src = qkv + (size_t)b * SEQ * QKVN + VOFF + kh * HD;
#pragma unroll
    for (int i = 0; i < 32; i += 8)
        t[ty + i][tx] = src[(size_t)(s0 + ty + i) * QKVN + d0 + tx];
    __syncthreads();
    __bf16* dst = vtg + ((size_t)z * HD + d0) * VSTR + s0;
#pragma unroll
    for (int i = 0; i < 32; i += 8)
        dst[(size_t)(ty + i) * VSTR + tx] = t[tx][ty + i];
}

// ---------------- bf16 GEMM, 128x64 tile, BK=64, double-buffered LDS ----------------
// C[M,N] = A[M,K]*Bt[N,K]^T + bias. 1D grid, bijective XCD swizzle.
// 4 waves (2Mx2N), wave = 64x32 output (4x2 frags). XOR-swizzled staging
// (pre-swizzled GLL source, linear LDS dest; frag reads 2-way = free).
// Double-buffer: STAGE(s+1) issued BEFORE compute(s) -> the single barrier's
// vmcnt drain is covered by ~1500 cyc of MFMA. One barrier per k-step.
template<int OUT_BF16, int QSCALE>
__global__ __launch_bounds__(256) void gemm_bf16(
    const __bf16* __restrict__ A, const __bf16* __restrict__ Bt,
    const float* __restrict__ bias, void* __restrict__ Cout,
    int M, int N, int K, int nx)
{
    __shared__ __bf16 Als[2][128 * 64];   // [buf][row][unit^] swizzled
    __shared__ __bf16 Bls[2][64 * 64];
    const int tid  = threadIdx.x;
    const int lane = tid & 63;
    const int wave = tid >> 6;
    const int lo = lane & 15, hi = lane >> 4;

    const int lin = blockIdx.x;
    const int cpx = gridDim.x >> 3;                    // grid % 8 == 0
    const int swz = (lin & 7) * cpx + (lin >> 3);      // XCD-contiguous
    const int bm = (swz / nx) * 128, bn = (swz % nx) * 64;
    const int wr = (wave >> 1) * 64, wc = (wave & 1) * 32;

    // staging: instr covers 8 rows (lane>>3), unit lane&7; source unit pre-XORed
    const int srow = lane >> 3;                        // 0..7
    const int sun  = ((lane & 7) ^ srow) * 8;          // elems
    const __bf16* gA = A  + (size_t)(bm + wave * 32 + srow) * K + sun;
    const __bf16* gB = Bt + (size_t)(bn + wave * 16 + srow) * K + sun;
    __bf16* lA0 = &Als[0][wave * 32 * 64];
    __bf16* lB0 = &Bls[0][wave * 16 * 64];

#define GSTAGE(k0, buf)                                          \
    do {                                                         \
        __bf16* la = lA0 + (buf) * (128 * 64);                   \
        __bf16* lb = lB0 + (buf) * (64 * 64);                    \
        GLL16(gA + (k0),                  la);                   \
        GLL16(gA + (k0) + (size_t)8  * K, la + 512);             \
        GLL16(gA + (k0) + (size_t)16 * K, la + 1024);            \
        GLL16(gA + (k0) + (size_t)24 * K, la + 1536);            \
        GLL16(gB + (k0),                  lb);                   \
        GLL16(gB + (k0) + (size_t)8  * K, lb + 512);             \
    } while (0)

    // swizzled fragment-read unit offsets: ksub 0 -> units hi, ksub 1 -> hi+4
    const int xk = lo & 7;
    const int u0 = (hi ^ xk) * 8;
    const int u1 = ((hi + 4) ^ xk) * 8;

    f32x4 acc[4][2] = {};

    const int NS = K >> 6;                 // k-steps of 64
    GSTAGE(0, 0);
    __syncthreads();

    int cur = 0;
    for (int s = 0; s < NS; ++s) {
        if (s + 1 < NS) GSTAGE((size_t)(s + 1) << 6, cur ^ 1);   // in flight under compute

#pragma unroll
        for (int ksub = 0; ksub < 2; ksub++) {
            const int uu = ksub ? u1 : u0;
            bf16x8 af[4], bfr[2];
#pragma unroll
            for (int i = 0; i < 4; i++)
                af[i] = *reinterpret_cast<const bf16x8*>(&Als[cur][(wr + i * 16 + lo) * 64 + uu]);
#pragma unroll
            for (int j = 0; j < 2; j++)
                bfr[j] = *reinterpret_cast<const bf16x8*>(&Bls[cur][(wc + j * 16 + lo) * 64 + uu]);
#pragma unroll
            for (int i = 0; i < 4; i++)
#pragma unroll
                for (int j = 0; j < 2; j++)
                    acc[i][j] = __builtin_amdgcn_mfma_f32_16x16x32_bf16(af[i], bfr[j], acc[i][j], 0, 0, 0);
        }

        __syncthreads();   // reads of buf(cur) done; GSTAGE(s+1) drained
        cur ^= 1;
    }
#undef GSTAGE

#pragma unroll
    for (int j = 0; j < 2; j++) {
        int col = bn + wc + j * 16 + lo;
        float bv = bias[col];
#pragma unroll
        for (int i = 0; i < 4; i++) {
            int row0 = bm + wr + i * 16 + hi * 4;
#pragma unroll
            for (int rr = 0; rr < 4; rr++) {
                float v = acc[i][j][rr] + bv;
                if (QSCALE && col < DIMD) v *= CSC;
                if (OUT_BF16) ((__bf16*)Cout)[(size_t)(row0 + rr) * N + col] = (__bf16)v;
                else          ((float* )Cout)[(size_t)(row0 + rr) * N + col] = v;
            }
        }
    }
}

// ---------------- causal GQA flash attention (r14 structure, proven 45.8us) ----------------
// 512 blocks x 512 threads = 8 waves = 4 heads x 2 key-parities. bid&7 = b*4+kh
// (XCD pin). Each wave handles tiles A=p, B=127-p (16 q-rows each) over its
// parity's 64-key chunks. 128-key super-chunks staged once per block
// (K[128][64], Vt[64][128], XOR-swizzled source, single-buffered). Fixed-max
// exp2 softmax -> split-K is a pure sum.
__global__ __launch_bounds__(512, 4) void attn_fwd(
    const __bf16* __restrict__ qkv, const __bf16* __restrict__ vt, __bf16* __restrict__ y)
{
    __shared__ __bf16 Kls[128 * 64];        // [key][d], row-XOR-swizzled 16B units
    __shared__ __bf16 Vls[64 * 128];        // [d][key], row-XOR-swizzled 16B units
    __shared__ __bf16 Pls[8][2][16][72];    // [wave][tile][q][k], 144B rows
    const int tid  = threadIdx.x;
    const int wave = tid >> 6, lane = tid & 63;
    const int lo = lane & 15, hi = lane >> 4;
    const int head = wave & 3, par = wave >> 2;

    const int bid = blockIdx.x;
    const int z  = bid & 7;              // b*4 + kh  -> XCD-pinned
    const int b  = z >> 2, kh = z & 3;
    const int p  = bid >> 3;             // 0..63
    const int h  = kh * 4 + head;

    const int TA = p, TB = 127 - p;
    const int qwA = TA * 16, qwB = TB * 16;
    const int cA = (TA >> 2) + 1, cB = (TB >> 2) + 1;   // 64-key chunk counts
    const int nsc = (cB + 1) >> 1;                      // 128-key super-chunks

    const __bf16* base = qkv + (size_t)b * SEQ * QKVN;
    const __bf16* qp = base + h * HD;
    const __bf16* kp = base + DIMD + kh * HD;
    const __bf16* vp = vt + (size_t)z * HD * VSTR;      // [64][VSTR]

    // ---- staging sources (XOR-pre-swizzled; LDS dest linear) ----
    const int srow = lane >> 3;                       // 0..7
    const int sun  = ((lane & 7) ^ srow) * 8;
    const __bf16* kst0 = kp + (size_t)(wave * 16 + srow) * QKVN + sun;
    const __bf16* kst1 = kp + (size_t)(wave * 16 + 8 + srow) * QKVN + sun;
    const int vrow = lane >> 4;                       // 0..3
    const int vun0 = ((lane & 15) ^ vrow) * 8;
    const int vun1 = ((lane & 15) ^ (vrow + 4)) * 8;
    const __bf16* vst0 = vp + (size_t)(wave * 8 + vrow) * VSTR + vun0;
    const __bf16* vst1 = vp + (size_t)(wave * 8 + 4 + vrow) * VSTR + vun1;
    __bf16* kdst = &Kls[wave * 1024];
    __bf16* vdst = &Vls[wave * 1024];

#define STAGE(s)                                            \
    do {                                                    \
        const size_t ko = (size_t)(s) * 128 * QKVN;         \
        const int    vo = (s) * 128;                        \
        GLL16(kst0 + ko, kdst);                             \
        GLL16(kst1 + ko, kdst + 512);                       \
        GLL16(vst0 + vo, vdst);                             \
        GLL16(vst1 + vo, vdst + 512);                       \
    } while (0)

    // ---- swizzled fragment-read offsets ----
    const int xk = lo & 7;
    const int u0 = (hi ^ xk) * 8;          // K d-units hi
    const int u1 = ((hi + 4) ^ xk) * 8;    // K d-units hi+4
    const int kb = par * 64;               // this parity's key base within tile

    // Q B-frags (pre-scaled by CSC in GEMM1): lane holds Q[qw+lo][hi*8..+8]
    bf16x8 bQA0 = *reinterpret_cast<const bf16x8*>(qp + (size_t)(qwA + lo) * QKVN + hi * 8);
    bf16x8 bQA1 = *reinterpret_cast<const bf16x8*>(qp + (size_t)(qwA + lo) * QKVN + 32 + hi * 8);
    bf16x8 bQB0 = *reinterpret_cast<const bf16x8*>(qp + (size_t)(qwB + lo) * QKVN + hi * 8);
    bf16x8 bQB1 = *reinterpret_cast<const bf16x8*>(qp + (size_t)(qwB + lo) * QKVN + 32 + hi * 8);

    f32x4 accA[4] = {}, accB[4] = {};
    float ssA = 0.0f, ssB = 0.0f;

    STAGE(0);
    __syncthreads();

    for (int s = 0; s < nsc; ++s) {
        const int ce = 2 * s + par;        // this wave's 64-key chunk index
        const int kt = ce << 6;            // global key base (mask arithmetic)
        const bool aB = (ce < cB), dB = (ce == cB - 1);
        const bool aA = (ce < cA), dA = (ce == cA - 1);

        if (aB) {
            // S^T = K Q^T per 16-key subtile; lane gets q=lo, k = kt+16ks+hi*4+r
#pragma unroll
            for (int ks = 0; ks < 4; ks++) {
                const __bf16* Kr = &Kls[(kb + ks * 16 + lo) * 64];
                bf16x8 aK0 = *reinterpret_cast<const bf16x8*>(Kr + u0);
                bf16x8 aK1 = *reinterpret_cast<const bf16x8*>(Kr + u1);

                {   // tile B
                    f32x4 sv = {0.f, 0.f, 0.f, 0.f};
                    sv = __builtin_amdgcn_mfma_f32_16x16x32_bf16(aK0, bQB0, sv, 0, 0, 0);
                    sv = __builtin_amdgcn_mfma_f32_16x16x32_bf16(aK1, bQB1, sv, 0, 0, 0);
                    bf16x4 pk;
#pragma unroll
                    for (int r = 0; r < 4; r++) {
                        float e = exp2f(sv[r]);
                        if (dB && (kt + ks * 16 + hi * 4 + r > qwB + lo)) e = 0.0f;
                        ssB += e;
                        pk[r] = (__bf16)e;
                    }
                    *reinterpret_cast<bf16x4*>(&Pls[wave][1][lo][ks * 16 + hi * 4]) = pk;
                }
                if (aA) {   // tile A — reuses aK0/aK1
                    f32x4 sv = {0.f, 0.f, 0.f, 0.f};
                    sv = __builtin_amdgcn_mfma_f32_16x16x32_bf16(aK0, bQA0, sv, 0, 0, 0);
                    sv = __builtin_amdgcn_mfma_f32_16x16x32_bf16(aK1, bQA1, sv, 0, 0, 0);
                    bf16x4 pk;
#pragma unroll
                    for (int r = 0; r < 4; r++) {
                        float e = exp2f(sv[r]);
                        if (dA && (kt + ks * 16 + hi * 4 + r > qwA + lo)) e = 0.0f;
                        ssA += e;
                        pk[r] = (__bf16)e;
                    }
                    *reinterpret_cast<bf16x4*>(&Pls[wave][0][lo][ks * 16 + hi * 4]) = pk;
                }
            }

            // P x V : V frags shared by both tiles
#pragma unroll
            for (int k2 = 0; k2 < 2; k2++) {
                const int uv = ((8 * par + k2 * 4 + hi) ^ xk) * 8;
                bf16x8 v0 = *reinterpret_cast<const bf16x8*>(&Vls[(0 * 16 + lo) * 128] + uv);
                bf16x8 v1 = *reinterpret_cast<const bf16x8*>(&Vls[(1 * 16 + lo) * 128] + uv);
                bf16x8 v2 = *reinterpret_cast<const bf16x8*>(&Vls[(2 * 16 + lo) * 128] + uv);
                bf16x8 v3 = *reinterpret_cast<const bf16x8*>(&Vls[(3 * 16 + lo) * 128] + uv);
                bf16x8 pB = *reinterpret_cast<const bf16x8*>(&Pls[wave][1][lo][k2 * 32 + hi * 8]);
                accB[0] = __builtin_amdgcn_mfma_f32_16x16x32_bf16(pB, v0, accB[0], 0, 0, 0);
                accB[1] = __builtin_amdgcn_mfma_f32_16x16x32_bf16(pB, v1, accB[1], 0, 0, 0);
                accB[2] = __builtin_amdgcn_mfma_f32_16x16x32_bf16(pB, v2, accB[2], 0, 0, 0);
                accB[3] = __builtin_amdgcn_mfma_f32_16x16x32_bf16(pB, v3, accB[3], 0, 0, 0);
                if (aA) {
                    bf16x8 pA = *reinterpret_cast<const bf16x8*>(&Pls[wave][0][lo][k2 * 32 + hi * 8]);
                    accA[0] = __builtin_amdgcn_mfma_f32_16x16x32_bf16(pA, v0, accA[0], 0, 0, 0);
                    accA[1] = __builtin_amdgcn_mfma_f32_16x16x32_bf16(pA, v1, accA[1], 0, 0, 0);
                    accA[2] = __builtin_amdgcn_mfma_f32_16x16x32_bf16(pA, v2, accA[2], 0, 0, 0);
                    accA[3] = __builtin_amdgcn_mfma_f32_16x16x32_bf16(pA, v3, accA[3], 0, 0, 0);
                }
            }
        }

        __syncthreads();                       // all reads of this super-chunk done
        if (s + 1 < nsc) {
            STAGE(s + 1);
            __syncthreads();                   // staged data visible
        }
    }
#undef STAGE

    // ---- parity combine (pure sum: fixed-max softmax) through LDS (overlays Pls) ----
    float* cls = (float*)&Pls[0][0][0][0];
    const int cbase = (head * 64 + lane) * 36;   // 144B stride, 16B-aligned
    if (par == 1) {
#pragma unroll
        for (int f = 0; f < 4; f++) {
            *reinterpret_cast<f32x4*>(&cls[cbase + f * 4])      = accA[f];
            *reinterpret_cast<f32x4*>(&cls[cbase + 16 + f * 4]) = accB[f];
        }
        cls[cbase + 32] = ssA;
        cls[cbase + 33] = ssB;
    }
    __syncthreads();
    if (par == 0) {
#pragma unroll
        for (int f = 0; f < 4; f++) {
            accA[f] += *reinterpret_cast<f32x4*>(&cls[cbase + f * 4]);
            accB[f] += *reinterpret_cast<f32x4*>(&cls[cbase + 16 + f * 4]);
        }
        ssA += cls[cbase + 32];
        ssB += cls[cbase + 33];

        ssA += __shfl_xor(ssA, 16);  ssA += __shfl_xor(ssA, 32);
        ssB += __shfl_xor(ssB, 16);  ssB += __shfl_xor(ssB, 32);
#pragma unroll
        for (int r = 0; r < 4; r++) {
            float srA = __shfl(ssA, hi * 4 + r);
            float srB = __shfl(ssB, hi * 4 + r);
            float invA = 1.0f / srA, invB = 1.0f / srB;
            int qA = qwA + hi * 4 + r, qB = qwB + hi * 4 + r;
#pragma unroll
            for (int f = 0; f < 4; f++) {
                y[(size_t)(b * SEQ + qA) * DIMD + h * HD + f * 16 + lo] = (__bf16)(accA[f][r] * invA);
                y[(size_t)(b * SEQ + qB) * DIMD + h * HD + f * 16 + lo] = (__bf16)(accB[f][r] * invB);
            }
        }
    }
}

// ---------------- launcher ----------------
extern "C" void kernel_launch(void* const* d_in, const int* in_sizes, int n_in,
                              void* d_out, int out_size, void* d_ws, size_t ws_size,
                              hipStream_t stream) {
    const float* x    = (const float*)d_in[0];
    const float* Wqkv = (const float*)d_in[1];
    const float* bqkv = (const float*)d_in[2];
    const float* Wout = (const float*)d_in[3];
    const float* bout = (const float*)d_in[4];
    float* out = (float*)d_out;

    char* ws = (char*)d_ws;
    __bf16* xb    = (__bf16*)(ws);                          // 8 MB  (x bf16; later reused as y)
    __bf16* wqkvT = (__bf16*)(ws + ((size_t)8  << 20));     // 3 MB  [1536][1024] (dead after GEMM1)
    __bf16* woutT = (__bf16*)(ws + ((size_t)11 << 20));     // 2 MB  [1024][1024]
    __bf16* qkvb  = (__bf16*)(ws + ((size_t)13 << 20));     // 12 MB [4096][1536]
    __bf16* vtg   = wqkvT;                                  // alias: 2.2 MB Vt[8][64][VSTR]
    __bf16* yb    = xb;                                     // alias: xb dead after GEMM1

    const int M = NB * SEQ;   // 4096

    prep<<<6656, 256, 0, stream>>>(x, xb, Wqkv, wqkvT, Wout, woutT);

    // 128x64 tiles, BK=64, dbuf: 768 blocks (3/CU), XCD-swizzled
    gemm_bf16<1, 1><<<(M / 128) * (QKVN / 64), 256, 0, stream>>>(
        xb, wqkvT, bqkv, qkvb, M, QKVN, DIMD, QKVN / 64);

    transpose_v<<<dim3(SEQ / 32, HD / 32, NB * 4), dim3(32, 8), 0, stream>>>(qkvb, vtg);

    attn_fwd<<<512, 512, 0, stream>>>(qkvb, vtg, yb);

    // 128x64 tiles, BK=64, dbuf: 512 blocks (2/CU), XCD-swizzled
    gemm_bf16<0, 0><<<(M / 128) * (DIMD / 64), 256, 0, stream>>>(
        yb, woutT, bout, out, M, DIMD, DIMD, DIMD / 64);
}